// Round 8
// baseline (2652.942 us; speedup 1.0000x reference)
//
#include <hip/hip_runtime.h>
#include <hip/hip_bf16.h>
#include <stdint.h>

// BitLinear: out = x @ (sign(W)*(|W|>0.7*mean|W|)*scale)^T
// M=16384 (8*2048), K=4096, N=16384. All f32 in/out.
// Round 8: B (ternary W) bypasses LDS -> per-wave global->register loads in
// MFMA fragment layout (L2/L1-resident panel via clustered XCD map). LDS holds
// A only: 4 rotating 16KB buffers. LDS traffic/block-tile 128KB -> 80KB.
// Keeps r6's MFMA<->ds_read interleave + validated A-read swizzle (16x16x32,
// 0 conflicts) + counted vmcnt (steady-state 12, tail 10/8), 1 barrier/tile.
// Prep kernels byte-identical to rounds 1-7.

typedef __attribute__((ext_vector_type(8))) __bf16 bf16x8;
typedef __attribute__((ext_vector_type(4))) float f32x4;
typedef __attribute__((ext_vector_type(8))) unsigned short u16x8;

#define M_ROWS 16384
#define K_DIM  4096
#define N_DIM  16384

#define RED_BLOCKS 2048

// ---------- kernel 1a: per-block partial sums of |W| (deterministic) ----------
__global__ void absum_part_kernel(const float4* __restrict__ W4,
                                  double* __restrict__ part, long long n4) {
  double s = 0.0;
  const long long stride = (long long)gridDim.x * blockDim.x;
  for (long long i = (long long)blockIdx.x * blockDim.x + threadIdx.x; i < n4; i += stride) {
    float4 v = W4[i];
    s += (double)fabsf(v.x);
    s += (double)fabsf(v.y);
    s += (double)fabsf(v.z);
    s += (double)fabsf(v.w);
  }
  for (int o = 32; o > 0; o >>= 1) s += __shfl_down(s, o, 64);
  __shared__ double p[4];
  if ((threadIdx.x & 63) == 0) p[threadIdx.x >> 6] = s;
  __syncthreads();
  if (threadIdx.x == 0) part[blockIdx.x] = p[0] + p[1] + p[2] + p[3];
}

// ---------- kernel 1b: reduce partials -> total sum ----------
__global__ void reduce_sum_kernel(const double* __restrict__ part,
                                  double* __restrict__ sum, int n) {
  double s = 0.0;
  for (int i = threadIdx.x; i < n; i += blockDim.x) s += part[i];
  for (int o = 32; o > 0; o >>= 1) s += __shfl_down(s, o, 64);
  __shared__ double p[4];
  if ((threadIdx.x & 63) == 0) p[threadIdx.x >> 6] = s;
  __syncthreads();
  if (threadIdx.x == 0) *sum = p[0] + p[1] + p[2] + p[3];
}

// ---------- kernel 2: ternary-quantize W -> bf16 bit patterns ----------
__device__ __forceinline__ unsigned short tern_bf16(float w, float thr) {
  return (fabsf(w) > thr) ? ((w > 0.0f) ? (unsigned short)0x3F80u
                                        : (unsigned short)0xBF80u)
                          : (unsigned short)0u;
}

__global__ void quant_w_kernel(const float4* __restrict__ W4,
                               unsigned short* __restrict__ Wq,
                               const double* __restrict__ sum_ptr, long long n8) {
  const double mean = *sum_ptr / (double)((long long)N_DIM * K_DIM);
  const float thr = (float)(0.7 * mean);
  const long long stride = (long long)gridDim.x * blockDim.x;
  for (long long i = (long long)blockIdx.x * blockDim.x + threadIdx.x; i < n8; i += stride) {
    float4 a = W4[2 * i];
    float4 b = W4[2 * i + 1];
    u16x8 q;
    q[0] = tern_bf16(a.x, thr); q[1] = tern_bf16(a.y, thr);
    q[2] = tern_bf16(a.z, thr); q[3] = tern_bf16(a.w, thr);
    q[4] = tern_bf16(b.x, thr); q[5] = tern_bf16(b.y, thr);
    q[6] = tern_bf16(b.z, thr); q[7] = tern_bf16(b.w, thr);
    *(u16x8*)(Wq + i * 8) = q;
  }
}

// ---------- kernel 3: x f32 -> bf16 (RNE) ----------
__device__ __forceinline__ unsigned short f32_to_bf16_rne(float f) {
  unsigned int u = __float_as_uint(f);
  u += 0x7FFFu + ((u >> 16) & 1u);
  return (unsigned short)(u >> 16);
}

__global__ void cvt_x_kernel(const float4* __restrict__ X4,
                             unsigned short* __restrict__ Xb, long long n8) {
  const long long stride = (long long)gridDim.x * blockDim.x;
  for (long long i = (long long)blockIdx.x * blockDim.x + threadIdx.x; i < n8; i += stride) {
    float4 a = X4[2 * i];
    float4 b = X4[2 * i + 1];
    u16x8 q;
    q[0] = f32_to_bf16_rne(a.x); q[1] = f32_to_bf16_rne(a.y);
    q[2] = f32_to_bf16_rne(a.z); q[3] = f32_to_bf16_rne(a.w);
    q[4] = f32_to_bf16_rne(b.x); q[5] = f32_to_bf16_rne(b.y);
    q[6] = f32_to_bf16_rne(b.z); q[7] = f32_to_bf16_rne(b.w);
    *(u16x8*)(Xb + i * 8) = q;
  }
}

// ---------- kernel 4: bf16 GEMM, 256x256, BK=32, A-in-LDS / B-in-regs ----------
#define BM 256
#define BN 256
#define BK 32
#define NT (K_DIM / BK)   // 128

__global__ __launch_bounds__(512, 2) void gemm_bt_kernel(
    const unsigned short* __restrict__ A,   // [M][K] bf16 bits
    const unsigned short* __restrict__ B,   // [N][K] bf16 bits (ternary)
    float* __restrict__ C,                  // [M][N] f32
    const float* __restrict__ scale_ptr) {
  constexpr int K = K_DIM, N = N_DIM;
  // 4 rotating A-buffers x 256 rows x 32 shorts = 64 KiB
  __shared__ __align__(16) unsigned short lds[4][BM][BK];

  const int tid = threadIdx.x;
  const int wave = tid >> 6;      // 0..7
  const int lane = tid & 63;

  // 2D-clustered XCD map (r7-validated: FETCH -> ~1.6GB): XCD x owns bn-slab
  // [8x,8x+8); co-resident batches of 32 wgs form 4bm x 8bn rectangles.
  const int x = blockIdx.x & 7;   // XCD
  const int l = blockIdx.x >> 3;  // 0..511 within XCD
  const int g = l >> 5;           // round 0..15
  const int s = l & 31;           // position in 4x8 rectangle
  const int bm = g * 4 + (s & 3); // 0..63
  const int bn = x * 8 + (s >> 2);// 0..63

  const int wr = wave >> 2;       // 0..1  (128 rows each)
  const int wc = wave & 3;        // 0..3  (64 cols each)

  const unsigned short* Ag = A + (size_t)(bm * BM) * K;
  // Per-wave B fragment base: row = bn*256 + wc*64 + (lane&15), k-slot = (lane>>4)*8
  const unsigned short* Bw = B + (size_t)(bn * BN + wc * 64 + (lane & 15)) * K + (lane >> 4) * 8;

  // A staging: chunk = 16 rows x 64B; LDS dest linear; bank swizzle applied
  // inverse at the global source (rule 21): LDS[r][s'] = G[r][(s'-(r>>1))&3].
  const int strow = lane >> 2;                               // row in chunk 0..15
  const int scol = ((((lane & 3) - (lane >> 3)) & 3) << 3);  // src col in shorts

  // A fragment read (r6-validated, 0 conflicts): row = base16 + (lane&15);
  // read slot' = ((lane>>4) + (row>>1)) & 3
  const int frow = lane & 15;
  const int fsw = ((((lane >> 4) + ((lane & 15) >> 1)) & 3) << 3);  // shorts

#define STAGE_A(u)                                                                   \
  {                                                                                  \
    unsigned short* Ab_ = &lds[(u) & 3][0][0];                                       \
    _Pragma("unroll")                                                                \
    for (int i_ = 0; i_ < 2; ++i_) {                                                 \
      const int ch_ = wave * 2 + i_;                                                 \
      const int row_ = ch_ * 16 + strow;                                             \
      __builtin_amdgcn_global_load_lds(                                              \
          (__attribute__((address_space(1))) void*)(Ag + (size_t)row_ * K + (u) * BK + scol), \
          (__attribute__((address_space(3))) void*)(Ab_ + ch_ * 16 * BK), 16, 0, 0); \
    }                                                                                \
  }

#define LOADB(u, BF)                                                                 \
  {                                                                                  \
    _Pragma("unroll")                                                                \
    for (int n_ = 0; n_ < 4; ++n_)                                                   \
      BF[n_] = *(const bf16x8*)(Bw + (size_t)n_ * 16 * K + (u) * BK);                \
  }

#define RD_A(P, m_) (*(const bf16x8*)((P) + (wr * 128 + (m_) * 16 + frow) * BK + fsw))

#define MF4(m_, CA, CB)                                                              \
  {                                                                                  \
    _Pragma("unroll")                                                                \
    for (int n_ = 0; n_ < 4; ++n_)                                                   \
      acc[m_][n_] = __builtin_amdgcn_mfma_f32_16x16x32_bf16(CA[m_], CB[n_],          \
                                                            acc[m_][n_], 0, 0, 0);   \
  }

#define SB __builtin_amdgcn_sched_barrier(0)

  // iter: issue B(t+1)->regs + stage A(t+3)->LDS; counted vmcnt(12) retires
  // exactly A(t+1) (steady-state outstanding = 14: [A(t+1),B(t),A(t+2),
  // B(t+1),A(t+3)]); barrier; lgkm(0) [A(t) frags + last iter's reads done];
  // MFMA cluster with A(t+1) ds_reads threaded in. Compiler emits its own
  // counted vmcnt for the B(t) register operands (~8). Never drains.
#define ITER(T, CA, CB, NA, NB)                                                      \
  {                                                                                  \
    const int rd_ = ((T) + 1 < NT);                                                  \
    if (rd_) LOADB((T) + 1, NB);                                                     \
    if ((T) + 3 < NT) STAGE_A((T) + 3);                                              \
    SB;                                                                              \
    if ((T) < NT - 3) {                                                              \
      asm volatile("s_waitcnt vmcnt(12)" ::: "memory");                              \
    } else if ((T) == NT - 3) {                                                      \
      asm volatile("s_waitcnt vmcnt(10)" ::: "memory");                              \
    } else if ((T) == NT - 2) {                                                      \
      asm volatile("s_waitcnt vmcnt(8)" ::: "memory");                               \
    }                                                                                \
    __builtin_amdgcn_s_barrier();                                                    \
    asm volatile("s_waitcnt lgkmcnt(0)" ::: "memory");                               \
    SB;                                                                              \
    const unsigned short* NAp_ = &lds[((T) + 1) & 3][0][0];                          \
    __builtin_amdgcn_s_setprio(1);                                                   \
    MF4(0, CA, CB);                                                                  \
    SB;                                                                              \
    if (rd_) { NA[0] = RD_A(NAp_, 0); NA[1] = RD_A(NAp_, 1); }                       \
    SB;                                                                              \
    MF4(1, CA, CB);                                                                  \
    SB;                                                                              \
    if (rd_) { NA[2] = RD_A(NAp_, 2); NA[3] = RD_A(NAp_, 3); }                       \
    SB;                                                                              \
    MF4(2, CA, CB);                                                                  \
    SB;                                                                              \
    if (rd_) { NA[4] = RD_A(NAp_, 4); NA[5] = RD_A(NAp_, 5); }                       \
    SB;                                                                              \
    MF4(3, CA, CB);                                                                  \
    SB;                                                                              \
    if (rd_) { NA[6] = RD_A(NAp_, 6); NA[7] = RD_A(NAp_, 7); }                       \
    SB;                                                                              \
    MF4(4, CA, CB);                                                                  \
    MF4(5, CA, CB);                                                                  \
    MF4(6, CA, CB);                                                                  \
    MF4(7, CA, CB);                                                                  \
    __builtin_amdgcn_s_setprio(0);                                                   \
    SB;                                                                              \
  }

  f32x4 acc[8][4] = {};
  bf16x8 af0[8], bf0[4], af1[8], bf1[4];

  // ---------- prologue ----------
  STAGE_A(0);
  STAGE_A(1);
  STAGE_A(2);
  LOADB(0, bf0);
  // outstanding: A0(2) A1(2) A2(2) B0(4) = 10; vmcnt(4) retires A0,A1,A2.
  asm volatile("s_waitcnt vmcnt(4)" ::: "memory");
  __builtin_amdgcn_s_barrier();
  SB;
#pragma unroll
  for (int m = 0; m < 8; ++m) af0[m] = RD_A(&lds[0][0][0], m);
  SB;

  for (int t = 0; t < NT; t += 2) {
    ITER(t, af0, bf0, af1, bf1);
    ITER(t + 1, af1, bf1, af0, bf0);
  }
#undef ITER
#undef SB
#undef MF4
#undef RD_A
#undef LOADB
#undef STAGE_A

  // ---------------- epilogue ----------------
  const float scale = *scale_ptr;
  const int crow0 = bm * BM + wr * 128;
  const int ccol0 = bn * BN + wc * 64;
#pragma unroll
  for (int m = 0; m < 8; ++m)
#pragma unroll
    for (int n = 0; n < 4; ++n)
#pragma unroll
      for (int j = 0; j < 4; ++j) {
        // C/D layout (m89-verified): col = lane&15, row = (lane>>4)*4 + j
        const int row = crow0 + m * 16 + ((lane >> 4) << 2) + j;
        const int col = ccol0 + n * 16 + (lane & 15);
        C[(size_t)row * N + col] = acc[m][n][j] * scale;
      }
}

extern "C" void kernel_launch(void* const* d_in, const int* in_sizes, int n_in,
                              void* d_out, int out_size, void* d_ws, size_t ws_size,
                              hipStream_t stream) {
  (void)in_sizes; (void)n_in; (void)out_size; (void)ws_size;
  const float* x = (const float*)d_in[0];
  const float* w = (const float*)d_in[1];
  const float* scale = (const float*)d_in[2];
  float* out = (float*)d_out;

  char* ws = (char*)d_ws;
  double* part = (double*)ws;
  double* sum = (double*)(ws + 16384);
  unsigned short* Wq = (unsigned short*)(ws + 32768);
  unsigned short* Xb = (unsigned short*)(ws + 32768 + (size_t)N_DIM * K_DIM * 2);

  const long long nW = (long long)N_DIM * K_DIM;   // 67108864
  const long long nX = (long long)M_ROWS * K_DIM;  // 67108864

  absum_part_kernel<<<RED_BLOCKS, 256, 0, stream>>>((const float4*)w, part, nW / 4);
  reduce_sum_kernel<<<1, 256, 0, stream>>>(part, sum, RED_BLOCKS);
  quant_w_kernel<<<2048, 256, 0, stream>>>((const float4*)w, Wq, sum, nW / 8);
  cvt_x_kernel<<<2048, 256, 0, stream>>>((const float4*)x, Xb, nX / 8);

  const int nblocks = (M_ROWS / BM) * (N_DIM / BN);  // 4096
  gemm_bt_kernel<<<nblocks, 512, 0, stream>>>(Xb, Wq, out, scale);
}

// Round 9
// 2192.195 us; speedup vs baseline: 1.2102x; 1.2102x over previous
//
#include <hip/hip_runtime.h>
#include <hip/hip_bf16.h>
#include <stdint.h>

// BitLinear: out = x @ (sign(W)*(|W|>0.7*mean|W|)*scale)^T
// M=16384 (8*2048), K=4096, N=16384. All f32 in/out.
// Round 9: faithful m201 8-phase port. BK=64, dbuf=2 (A,B each [2][2][128][64],
// 128 KiB), 8 waves (2M x 4N), per-wave 128x64. Per phase: {ds_read frags
// (12/4/8/0); stage ONE half-tile (2 gload_lds); barrier; lgkm(0); setprio(1);
// 16 MFMA (one C-quadrant); setprio(0); barrier}. vmcnt(4) at phases 4 and 8
// ONLY. Stage order per iter: A0A1(t+1), B0B1(t+2), A0A1(t+2), B0B1(t+3) --
// each half staged one phase after its buffer's last read (race-free).
// 8-slot swizzle for 128B rows: slot' = (slot + (row&7))&7, inverse at the
// global source. r7 XCD cluster map retained. Prep kernels identical r1-r8.

typedef __attribute__((ext_vector_type(8))) __bf16 bf16x8;
typedef __attribute__((ext_vector_type(4))) float f32x4;
typedef __attribute__((ext_vector_type(8))) unsigned short u16x8;

#define M_ROWS 16384
#define K_DIM  4096
#define N_DIM  16384

#define RED_BLOCKS 2048

// ---------- kernel 1a: per-block partial sums of |W| (deterministic) ----------
__global__ void absum_part_kernel(const float4* __restrict__ W4,
                                  double* __restrict__ part, long long n4) {
  double s = 0.0;
  const long long stride = (long long)gridDim.x * blockDim.x;
  for (long long i = (long long)blockIdx.x * blockDim.x + threadIdx.x; i < n4; i += stride) {
    float4 v = W4[i];
    s += (double)fabsf(v.x);
    s += (double)fabsf(v.y);
    s += (double)fabsf(v.z);
    s += (double)fabsf(v.w);
  }
  for (int o = 32; o > 0; o >>= 1) s += __shfl_down(s, o, 64);
  __shared__ double p[4];
  if ((threadIdx.x & 63) == 0) p[threadIdx.x >> 6] = s;
  __syncthreads();
  if (threadIdx.x == 0) part[blockIdx.x] = p[0] + p[1] + p[2] + p[3];
}

// ---------- kernel 1b: reduce partials -> total sum ----------
__global__ void reduce_sum_kernel(const double* __restrict__ part,
                                  double* __restrict__ sum, int n) {
  double s = 0.0;
  for (int i = threadIdx.x; i < n; i += blockDim.x) s += part[i];
  for (int o = 32; o > 0; o >>= 1) s += __shfl_down(s, o, 64);
  __shared__ double p[4];
  if ((threadIdx.x & 63) == 0) p[threadIdx.x >> 6] = s;
  __syncthreads();
  if (threadIdx.x == 0) *sum = p[0] + p[1] + p[2] + p[3];
}

// ---------- kernel 2: ternary-quantize W -> bf16 bit patterns ----------
__device__ __forceinline__ unsigned short tern_bf16(float w, float thr) {
  return (fabsf(w) > thr) ? ((w > 0.0f) ? (unsigned short)0x3F80u
                                        : (unsigned short)0xBF80u)
                          : (unsigned short)0u;
}

__global__ void quant_w_kernel(const float4* __restrict__ W4,
                               unsigned short* __restrict__ Wq,
                               const double* __restrict__ sum_ptr, long long n8) {
  const double mean = *sum_ptr / (double)((long long)N_DIM * K_DIM);
  const float thr = (float)(0.7 * mean);
  const long long stride = (long long)gridDim.x * blockDim.x;
  for (long long i = (long long)blockIdx.x * blockDim.x + threadIdx.x; i < n8; i += stride) {
    float4 a = W4[2 * i];
    float4 b = W4[2 * i + 1];
    u16x8 q;
    q[0] = tern_bf16(a.x, thr); q[1] = tern_bf16(a.y, thr);
    q[2] = tern_bf16(a.z, thr); q[3] = tern_bf16(a.w, thr);
    q[4] = tern_bf16(b.x, thr); q[5] = tern_bf16(b.y, thr);
    q[6] = tern_bf16(b.z, thr); q[7] = tern_bf16(b.w, thr);
    *(u16x8*)(Wq + i * 8) = q;
  }
}

// ---------- kernel 3: x f32 -> bf16 (RNE) ----------
__device__ __forceinline__ unsigned short f32_to_bf16_rne(float f) {
  unsigned int u = __float_as_uint(f);
  u += 0x7FFFu + ((u >> 16) & 1u);
  return (unsigned short)(u >> 16);
}

__global__ void cvt_x_kernel(const float4* __restrict__ X4,
                             unsigned short* __restrict__ Xb, long long n8) {
  const long long stride = (long long)gridDim.x * blockDim.x;
  for (long long i = (long long)blockIdx.x * blockDim.x + threadIdx.x; i < n8; i += stride) {
    float4 a = X4[2 * i];
    float4 b = X4[2 * i + 1];
    u16x8 q;
    q[0] = f32_to_bf16_rne(a.x); q[1] = f32_to_bf16_rne(a.y);
    q[2] = f32_to_bf16_rne(a.z); q[3] = f32_to_bf16_rne(a.w);
    q[4] = f32_to_bf16_rne(b.x); q[5] = f32_to_bf16_rne(b.y);
    q[6] = f32_to_bf16_rne(b.z); q[7] = f32_to_bf16_rne(b.w);
    *(u16x8*)(Xb + i * 8) = q;
  }
}

// ---------- kernel 4: bf16 GEMM, 256x256, BK=64, 8-phase m201 schedule ----------
#define BM 256
#define BN 256
#define BK 64
#define NT (K_DIM / BK)   // 64

__global__ __launch_bounds__(512, 2) void gemm_bt_kernel(
    const unsigned short* __restrict__ A,   // [M][K] bf16 bits
    const unsigned short* __restrict__ B,   // [N][K] bf16 bits (ternary)
    float* __restrict__ C,                  // [M][N] f32
    const float* __restrict__ scale_ptr) {
  constexpr int K = K_DIM, N = N_DIM;
  // [dbuf][half][row-in-half][col] bf16 : 64 KiB each
  __shared__ __align__(16) unsigned short Alds[2][2][128][BK];
  __shared__ __align__(16) unsigned short Blds[2][2][128][BK];

  const int tid = threadIdx.x;
  const int wave = tid >> 6;      // 0..7
  const int lane = tid & 63;

  // 2D-clustered XCD map (r7-validated: FETCH ~1.57GB)
  const int x = blockIdx.x & 7;   // XCD
  const int l = blockIdx.x >> 3;  // 0..511 within XCD
  const int g = l >> 5;
  const int s = l & 31;
  const int bm = g * 4 + (s & 3); // 0..63
  const int bn = x * 8 + (s >> 2);// 0..63

  const int wr = wave >> 2;       // 0..1: A half (128 rows)
  const int wc = wave & 3;        // 0..3: 64 B rows
  const int bh = wc >> 1;         // B half
  const int bl0 = (wc & 1) * 64;  // B row base within half

  const unsigned short* Ag = A + (size_t)(bm * BM) * K;
  const unsigned short* Bg = B + (size_t)(bn * BN) * K;

  // staging: chunk = 8 rows x 128B = 1024B per gload_lds; lane -> (row l>>3,
  // slot l&7). Inverse swizzle at source: LDS[r][slot] = G[r][(slot-(r&7))&7].
  const int rr = lane >> 3;                          // row in chunk
  const int scl = (((lane & 7) - rr) & 7) << 3;      // src col in shorts

  // fragment read: row-in-half = base16 + frow; slot' = (kh*4+qq+(row&7))&7
  // (2-deep uniform per quarter-wave -> 0 bank conflicts)
  const int frow = lane & 15;
  const int qq = lane >> 4;       // 0..3
  const int sw7 = lane & 7;       // == frow&7 (bases are mult of 8 rows)

#define STAGE_AH(u, h)                                                               \
  { _Pragma("unroll") for (int i_ = 0; i_ < 2; ++i_) {                               \
      const int ch_ = wave * 2 + i_;                                                 \
      __builtin_amdgcn_global_load_lds(                                              \
          (__attribute__((address_space(1))) void*)(                                 \
              Ag + (size_t)((h) * 128 + ch_ * 8 + rr) * K + (u) * BK + scl),         \
          (__attribute__((address_space(3))) void*)(&Alds[(u) & 1][(h)][ch_ * 8][0]),\
          16, 0, 0); } }

#define STAGE_BH(u, h)                                                               \
  { _Pragma("unroll") for (int i_ = 0; i_ < 2; ++i_) {                               \
      const int ch_ = wave * 2 + i_;                                                 \
      __builtin_amdgcn_global_load_lds(                                              \
          (__attribute__((address_space(1))) void*)(                                 \
              Bg + (size_t)((h) * 128 + ch_ * 8 + rr) * K + (u) * BK + scl),         \
          (__attribute__((address_space(3))) void*)(&Blds[(u) & 1][(h)][ch_ * 8][0]),\
          16, 0, 0); } }

#define RD4A(DST, q_, M0)                                                            \
  { _Pragma("unroll") for (int m_ = 0; m_ < 4; ++m_)                                 \
      _Pragma("unroll") for (int kh_ = 0; kh_ < 2; ++kh_)                            \
        DST[m_][kh_] = *(const bf16x8*)(&Alds[q_][wr][(M0 + m_) * 16 + frow][0] +    \
                                        (((kh_ * 4 + qq + sw7) & 7) << 3)); }

#define RD2B(DST, q_, N0)                                                            \
  { _Pragma("unroll") for (int n_ = 0; n_ < 2; ++n_)                                 \
      _Pragma("unroll") for (int kh_ = 0; kh_ < 2; ++kh_)                            \
        DST[n_][kh_] = *(const bf16x8*)(&Blds[q_][bh][bl0 + (N0 + n_) * 16 + frow][0] + \
                                        (((kh_ * 4 + qq + sw7) & 7) << 3)); }

#define MFQ(M0, N0, AF, BF)                                                          \
  { _Pragma("unroll") for (int m_ = 0; m_ < 4; ++m_)                                 \
      _Pragma("unroll") for (int n_ = 0; n_ < 2; ++n_)                               \
        _Pragma("unroll") for (int kh_ = 0; kh_ < 2; ++kh_)                          \
          acc[M0 + m_][N0 + n_] = __builtin_amdgcn_mfma_f32_16x16x32_bf16(           \
              AF[m_][kh_], BF[n_][kh_], acc[M0 + m_][N0 + n_], 0, 0, 0); }

#define SB __builtin_amdgcn_sched_barrier(0)
#define LGKM0 { asm volatile("s_waitcnt lgkmcnt(0)" ::: "memory"); SB; }
#define PRIO1 __builtin_amdgcn_s_setprio(1)
#define PRIO0 __builtin_amdgcn_s_setprio(0)

  f32x4 acc[8][4] = {};

  // ---------- prologue: tile0 (A,B) + tile1 (B) staged ----------
  STAGE_AH(0, 0); STAGE_AH(0, 1);
  STAGE_BH(0, 0); STAGE_BH(0, 1);
  STAGE_BH(1, 0); STAGE_BH(1, 1);
  asm volatile("s_waitcnt vmcnt(4)" ::: "memory");  // tile0 landed; B(1) in flight
  __builtin_amdgcn_s_barrier();
  SB;

  for (int t2 = 0; t2 < NT; t2 += 2) {
    const int g2 = (t2 + 2 < NT);
    bf16x8 afl[4][2], afh[4][2], bfl[2][2], bfh[2][2];

    // ================= tile t2 (buf 0) =================
    // P1: 12 reads; stage A0(t2+1)
    RD4A(afl, 0, 0); RD2B(bfl, 0, 0);
    STAGE_AH(t2 + 1, 0);
    asm volatile("s_waitcnt lgkmcnt(8)" ::: "memory");
    __builtin_amdgcn_s_barrier();
    LGKM0; PRIO1; MFQ(0, 0, afl, bfl); PRIO0;
    __builtin_amdgcn_s_barrier(); SB;
    // P2: 4 reads; stage A1(t2+1)
    RD2B(bfh, 0, 2);
    STAGE_AH(t2 + 1, 1);
    __builtin_amdgcn_s_barrier();
    LGKM0; PRIO1; MFQ(0, 2, afl, bfh); PRIO0;
    __builtin_amdgcn_s_barrier(); SB;
    // P3: 8 reads; stage B0(t2+2)
    RD4A(afh, 0, 4);
    if (g2) STAGE_BH(t2 + 2, 0);
    __builtin_amdgcn_s_barrier();
    LGKM0; PRIO1; MFQ(4, 0, afh, bfl); PRIO0;
    __builtin_amdgcn_s_barrier(); SB;
    // P4: 0 reads; stage B1(t2+2); counted vmcnt
    if (g2) STAGE_BH(t2 + 2, 1);
    __builtin_amdgcn_s_barrier();
    PRIO1; MFQ(4, 2, afh, bfh); PRIO0;
    if (g2) { asm volatile("s_waitcnt vmcnt(4)" ::: "memory"); }
    else    { asm volatile("s_waitcnt vmcnt(0)" ::: "memory"); }
    __builtin_amdgcn_s_barrier(); SB;

    // ================= tile t2+1 (buf 1) =================
    // P5: 12 reads; stage A0(t2+2)
    RD4A(afl, 1, 0); RD2B(bfl, 1, 0);
    if (g2) STAGE_AH(t2 + 2, 0);
    asm volatile("s_waitcnt lgkmcnt(8)" ::: "memory");
    __builtin_amdgcn_s_barrier();
    LGKM0; PRIO1; MFQ(0, 0, afl, bfl); PRIO0;
    __builtin_amdgcn_s_barrier(); SB;
    // P6: 4 reads; stage A1(t2+2)
    RD2B(bfh, 1, 2);
    if (g2) STAGE_AH(t2 + 2, 1);
    __builtin_amdgcn_s_barrier();
    LGKM0; PRIO1; MFQ(0, 2, afl, bfh); PRIO0;
    __builtin_amdgcn_s_barrier(); SB;
    // P7: 8 reads; stage B0(t2+3)
    RD4A(afh, 1, 4);
    if (g2) STAGE_BH(t2 + 3, 0);
    __builtin_amdgcn_s_barrier();
    LGKM0; PRIO1; MFQ(4, 0, afh, bfl); PRIO0;
    __builtin_amdgcn_s_barrier(); SB;
    // P8: 0 reads; stage B1(t2+3); counted vmcnt
    if (g2) STAGE_BH(t2 + 3, 1);
    __builtin_amdgcn_s_barrier();
    PRIO1; MFQ(4, 2, afh, bfh); PRIO0;
    if (g2) { asm volatile("s_waitcnt vmcnt(4)" ::: "memory"); }
    __builtin_amdgcn_s_barrier(); SB;
  }
#undef PRIO0
#undef PRIO1
#undef LGKM0
#undef SB
#undef MFQ
#undef RD2B
#undef RD4A
#undef STAGE_BH
#undef STAGE_AH

  // ---------------- epilogue ----------------
  const float scale = *scale_ptr;
  const int crow0 = bm * BM + wr * 128;
  const int ccol0 = bn * BN + wc * 64;
#pragma unroll
  for (int m = 0; m < 8; ++m)
#pragma unroll
    for (int n = 0; n < 4; ++n)
#pragma unroll
      for (int j = 0; j < 4; ++j) {
        // C/D layout (m89-verified): col = lane&15, row = (lane>>4)*4 + j
        const int row = crow0 + m * 16 + ((lane >> 4) << 2) + j;
        const int col = ccol0 + n * 16 + (lane & 15);
        C[(size_t)row * N + col] = acc[m][n][j] * scale;
      }
}

extern "C" void kernel_launch(void* const* d_in, const int* in_sizes, int n_in,
                              void* d_out, int out_size, void* d_ws, size_t ws_size,
                              hipStream_t stream) {
  (void)in_sizes; (void)n_in; (void)out_size; (void)ws_size;
  const float* x = (const float*)d_in[0];
  const float* w = (const float*)d_in[1];
  const float* scale = (const float*)d_in[2];
  float* out = (float*)d_out;

  char* ws = (char*)d_ws;
  double* part = (double*)ws;
  double* sum = (double*)(ws + 16384);
  unsigned short* Wq = (unsigned short*)(ws + 32768);
  unsigned short* Xb = (unsigned short*)(ws + 32768 + (size_t)N_DIM * K_DIM * 2);

  const long long nW = (long long)N_DIM * K_DIM;   // 67108864
  const long long nX = (long long)M_ROWS * K_DIM;  // 67108864

  absum_part_kernel<<<RED_BLOCKS, 256, 0, stream>>>((const float4*)w, part, nW / 4);
  reduce_sum_kernel<<<1, 256, 0, stream>>>(part, sum, RED_BLOCKS);
  quant_w_kernel<<<2048, 256, 0, stream>>>((const float4*)w, Wq, sum, nW / 8);
  cvt_x_kernel<<<2048, 256, 0, stream>>>((const float4*)x, Xb, nX / 8);

  const int nblocks = (M_ROWS / BM) * (N_DIM / BN);  // 4096
  gemm_bt_kernel<<<nblocks, 512, 0, stream>>>(Xb, Wq, out, scale);
}

// Round 10
// 2040.977 us; speedup vs baseline: 1.2998x; 1.0741x over previous
//
#include <hip/hip_runtime.h>
#include <hip/hip_bf16.h>
#include <stdint.h>

// BitLinear: out = x @ (sign(W)*(|W|>0.7*mean|W|)*scale)^T
// M=16384 (8*2048), K=4096, N=16384. All f32 in/out.
// Round 10: r6 exact schedule (16x16x32, 0-conflict swizzle, 1 barrier/tile,
// counted vmcnt(8), MFMA<->ds_read interleave) + r7 cluster map (FETCH 1.57GB)
// + DELETED cluster-entry lgkmcnt(0): compiler emits exact counted lgkm waits
// per consuming MFMA, so the LDS counter never drains in steady state.
// Prep kernels byte-identical to rounds 1-9.

typedef __attribute__((ext_vector_type(8))) __bf16 bf16x8;
typedef __attribute__((ext_vector_type(4))) float f32x4;
typedef __attribute__((ext_vector_type(8))) unsigned short u16x8;

#define M_ROWS 16384
#define K_DIM  4096
#define N_DIM  16384

#define RED_BLOCKS 2048

// ---------- kernel 1a: per-block partial sums of |W| (deterministic) ----------
__global__ void absum_part_kernel(const float4* __restrict__ W4,
                                  double* __restrict__ part, long long n4) {
  double s = 0.0;
  const long long stride = (long long)gridDim.x * blockDim.x;
  for (long long i = (long long)blockIdx.x * blockDim.x + threadIdx.x; i < n4; i += stride) {
    float4 v = W4[i];
    s += (double)fabsf(v.x);
    s += (double)fabsf(v.y);
    s += (double)fabsf(v.z);
    s += (double)fabsf(v.w);
  }
  for (int o = 32; o > 0; o >>= 1) s += __shfl_down(s, o, 64);
  __shared__ double p[4];
  if ((threadIdx.x & 63) == 0) p[threadIdx.x >> 6] = s;
  __syncthreads();
  if (threadIdx.x == 0) part[blockIdx.x] = p[0] + p[1] + p[2] + p[3];
}

// ---------- kernel 1b: reduce partials -> total sum ----------
__global__ void reduce_sum_kernel(const double* __restrict__ part,
                                  double* __restrict__ sum, int n) {
  double s = 0.0;
  for (int i = threadIdx.x; i < n; i += blockDim.x) s += part[i];
  for (int o = 32; o > 0; o >>= 1) s += __shfl_down(s, o, 64);
  __shared__ double p[4];
  if ((threadIdx.x & 63) == 0) p[threadIdx.x >> 6] = s;
  __syncthreads();
  if (threadIdx.x == 0) *sum = p[0] + p[1] + p[2] + p[3];
}

// ---------- kernel 2: ternary-quantize W -> bf16 bit patterns ----------
__device__ __forceinline__ unsigned short tern_bf16(float w, float thr) {
  return (fabsf(w) > thr) ? ((w > 0.0f) ? (unsigned short)0x3F80u
                                        : (unsigned short)0xBF80u)
                          : (unsigned short)0u;
}

__global__ void quant_w_kernel(const float4* __restrict__ W4,
                               unsigned short* __restrict__ Wq,
                               const double* __restrict__ sum_ptr, long long n8) {
  const double mean = *sum_ptr / (double)((long long)N_DIM * K_DIM);
  const float thr = (float)(0.7 * mean);
  const long long stride = (long long)gridDim.x * blockDim.x;
  for (long long i = (long long)blockIdx.x * blockDim.x + threadIdx.x; i < n8; i += stride) {
    float4 a = W4[2 * i];
    float4 b = W4[2 * i + 1];
    u16x8 q;
    q[0] = tern_bf16(a.x, thr); q[1] = tern_bf16(a.y, thr);
    q[2] = tern_bf16(a.z, thr); q[3] = tern_bf16(a.w, thr);
    q[4] = tern_bf16(b.x, thr); q[5] = tern_bf16(b.y, thr);
    q[6] = tern_bf16(b.z, thr); q[7] = tern_bf16(b.w, thr);
    *(u16x8*)(Wq + i * 8) = q;
  }
}

// ---------- kernel 3: x f32 -> bf16 (RNE) ----------
__device__ __forceinline__ unsigned short f32_to_bf16_rne(float f) {
  unsigned int u = __float_as_uint(f);
  u += 0x7FFFu + ((u >> 16) & 1u);
  return (unsigned short)(u >> 16);
}

__global__ void cvt_x_kernel(const float4* __restrict__ X4,
                             unsigned short* __restrict__ Xb, long long n8) {
  const long long stride = (long long)gridDim.x * blockDim.x;
  for (long long i = (long long)blockIdx.x * blockDim.x + threadIdx.x; i < n8; i += stride) {
    float4 a = X4[2 * i];
    float4 b = X4[2 * i + 1];
    u16x8 q;
    q[0] = f32_to_bf16_rne(a.x); q[1] = f32_to_bf16_rne(a.y);
    q[2] = f32_to_bf16_rne(a.z); q[3] = f32_to_bf16_rne(a.w);
    q[4] = f32_to_bf16_rne(b.x); q[5] = f32_to_bf16_rne(b.y);
    q[6] = f32_to_bf16_rne(b.z); q[7] = f32_to_bf16_rne(b.w);
    *(u16x8*)(Xb + i * 8) = q;
  }
}

// ---------- kernel 4: bf16 GEMM, 256x256, BK=32, MFMA<->ds_read interleave ----------
#define BM 256
#define BN 256
#define BK 32
#define NT (K_DIM / BK)   // 128

__global__ __launch_bounds__(512, 2) void gemm_bt_kernel(
    const unsigned short* __restrict__ A,   // [M][K] bf16 bits
    const unsigned short* __restrict__ B,   // [N][K] bf16 bits (ternary)
    float* __restrict__ C,                  // [M][N] f32
    const float* __restrict__ scale_ptr) {
  constexpr int K = K_DIM, N = N_DIM;
  // 4 rotating buffers x {A,B} x 256 rows x 32 shorts = 128 KiB
  __shared__ __align__(16) unsigned short lds[4][2][BM][BK];

  const int tid = threadIdx.x;
  const int wave = tid >> 6;      // 0..7
  const int lane = tid & 63;

  // 2D-clustered XCD map (r7-validated: FETCH ~1.57GB): XCD x owns bn-slab
  // [8x,8x+8); co-resident batches of 32 wgs form 4bm x 8bn rectangles.
  const int x = blockIdx.x & 7;   // XCD
  const int l = blockIdx.x >> 3;  // 0..511 within XCD
  const int g = l >> 5;           // round 0..15
  const int s = l & 31;           // position in 4x8 rectangle
  const int bm = g * 4 + (s & 3); // 0..63
  const int bn = x * 8 + (s >> 2);// 0..63

  const int wr = wave >> 2;       // 0..1  (128 rows each)
  const int wc = wave & 3;        // 0..3  (64 cols each)

  const unsigned short* Ag = A + (size_t)(bm * BM) * K;
  const unsigned short* Bg = B + (size_t)(bn * BN) * K;

  // staging: chunk = 16 rows x 64B; LDS dest linear; bank swizzle applied
  // inverse at the global source (rule 21), constants validated r4-r6.
  const int strow = lane >> 2;                               // row in chunk 0..15
  const int scol = ((((lane & 3) - (lane >> 3)) & 3) << 3);  // src col in shorts

  // fragment read (validated 0 conflicts): row = base16 + (lane&15);
  // slot' = ((lane>>4) + (row>>1)) & 3
  const int frow = lane & 15;
  const int fsw = ((((lane >> 4) + ((lane & 15) >> 1)) & 3) << 3);  // shorts

#define STAGE(u)                                                                     \
  {                                                                                  \
    const int kk0_ = (u) * BK;                                                       \
    unsigned short* Ab_ = &lds[(u) & 3][0][0][0];                                    \
    unsigned short* Bb_ = &lds[(u) & 3][1][0][0];                                    \
    _Pragma("unroll")                                                                \
    for (int i_ = 0; i_ < 2; ++i_) {                                                 \
      const int ch_ = wave * 2 + i_;                                                 \
      const int row_ = ch_ * 16 + strow;                                             \
      __builtin_amdgcn_global_load_lds(                                              \
          (__attribute__((address_space(1))) void*)(Ag + (size_t)row_ * K + kk0_ + scol), \
          (__attribute__((address_space(3))) void*)(Ab_ + ch_ * 16 * BK), 16, 0, 0); \
      __builtin_amdgcn_global_load_lds(                                              \
          (__attribute__((address_space(1))) void*)(Bg + (size_t)row_ * K + kk0_ + scol), \
          (__attribute__((address_space(3))) void*)(Bb_ + ch_ * 16 * BK), 16, 0, 0); \
    }                                                                                \
  }

#define RD_B(P, n_) (*(const bf16x8*)((P) + (wc * 64 + (n_) * 16 + frow) * BK + fsw))
#define RD_A(P, m_) (*(const bf16x8*)((P) + (wr * 128 + (m_) * 16 + frow) * BK + fsw))

#define MF4(m_, CA, CB)                                                              \
  {                                                                                  \
    _Pragma("unroll")                                                                \
    for (int n_ = 0; n_ < 4; ++n_)                                                   \
      acc[m_][n_] = __builtin_amdgcn_mfma_f32_16x16x32_bf16(CA[m_], CB[n_],          \
                                                            acc[m_][n_], 0, 0, 0);   \
  }

#define SB __builtin_amdgcn_sched_barrier(0)

  // iter: STAGE(t+3) -> counted vmcnt -> barrier -> MFMA cluster with frags(t+1)
  // reads threaded between groups. NO lgkm drain at entry: the compiler emits
  // exact counted lgkmcnt before each consuming MFMA (reads are IR-visible),
  // so lgkm never drains to 0 in steady state.
#define ITER(T, CA, CB, NA, NB, RD)                                                  \
  {                                                                                  \
    if ((T) + 3 < NT) STAGE((T) + 3);                                                \
    SB;                                                                              \
    if ((T) < NT - 3) {                                                              \
      asm volatile("s_waitcnt vmcnt(8)" ::: "memory");                               \
    } else if ((T) == NT - 3) {                                                      \
      asm volatile("s_waitcnt vmcnt(4)" ::: "memory");                               \
    } else if ((T) == NT - 2) {                                                      \
      asm volatile("s_waitcnt vmcnt(0)" ::: "memory");                               \
    }                                                                                \
    __builtin_amdgcn_s_barrier();                                                    \
    SB;                                                                              \
    const unsigned short* NAp_ = &lds[((T) + 1) & 3][0][0][0];                       \
    const unsigned short* NBp_ = &lds[((T) + 1) & 3][1][0][0];                       \
    __builtin_amdgcn_s_setprio(1);                                                   \
    MF4(0, CA, CB);                                                                  \
    SB;                                                                              \
    if (RD) { NB[0] = RD_B(NBp_, 0); NB[1] = RD_B(NBp_, 1); }                        \
    SB;                                                                              \
    MF4(1, CA, CB);                                                                  \
    SB;                                                                              \
    if (RD) { NB[2] = RD_B(NBp_, 2); NB[3] = RD_B(NBp_, 3); }                        \
    SB;                                                                              \
    MF4(2, CA, CB);                                                                  \
    SB;                                                                              \
    if (RD) { NA[0] = RD_A(NAp_, 0); NA[1] = RD_A(NAp_, 1); }                        \
    SB;                                                                              \
    MF4(3, CA, CB);                                                                  \
    SB;                                                                              \
    if (RD) { NA[2] = RD_A(NAp_, 2); NA[3] = RD_A(NAp_, 3); }                        \
    SB;                                                                              \
    MF4(4, CA, CB);                                                                  \
    SB;                                                                              \
    if (RD) { NA[4] = RD_A(NAp_, 4); NA[5] = RD_A(NAp_, 5); }                        \
    SB;                                                                              \
    MF4(5, CA, CB);                                                                  \
    SB;                                                                              \
    if (RD) { NA[6] = RD_A(NAp_, 6); NA[7] = RD_A(NAp_, 7); }                        \
    SB;                                                                              \
    MF4(6, CA, CB);                                                                  \
    MF4(7, CA, CB);                                                                  \
    __builtin_amdgcn_s_setprio(0);                                                   \
    SB;                                                                              \
  }

  f32x4 acc[8][4] = {};
  bf16x8 af0[8], bf0[4], af1[8], bf1[4];

  // ---------- prologue: stage 0,1,2; read frags(0) into set0 ----------
  STAGE(0);
  STAGE(1);
  STAGE(2);
  asm volatile("s_waitcnt vmcnt(8)" ::: "memory");  // tile 0 landed; 1,2 in flight
  __builtin_amdgcn_s_barrier();
  SB;
#pragma unroll
  for (int n = 0; n < 4; ++n) bf0[n] = RD_B(&lds[0][1][0][0], n);
#pragma unroll
  for (int m = 0; m < 8; ++m) af0[m] = RD_A(&lds[0][0][0][0], m);
  SB;

  for (int t = 0; t < NT - 2; t += 2) {
    ITER(t, af0, bf0, af1, bf1, 1);
    ITER(t + 1, af1, bf1, af0, bf0, 1);
  }
  ITER(NT - 2, af0, bf0, af1, bf1, 1);   // t = 126 (even): current set0
  ITER(NT - 1, af1, bf1, af0, bf0, 0);   // t = 127: no further reads
#undef ITER
#undef SB
#undef MF4
#undef RD_A
#undef RD_B
#undef STAGE

  // ---------------- epilogue ----------------
  const float scale = *scale_ptr;
  const int crow0 = bm * BM + wr * 128;
  const int ccol0 = bn * BN + wc * 64;
#pragma unroll
  for (int m = 0; m < 8; ++m)
#pragma unroll
    for (int n = 0; n < 4; ++n)
#pragma unroll
      for (int j = 0; j < 4; ++j) {
        // C/D layout (m89-verified): col = lane&15, row = (lane>>4)*4 + j
        const int row = crow0 + m * 16 + ((lane >> 4) << 2) + j;
        const int col = ccol0 + n * 16 + (lane & 15);
        C[(size_t)row * N + col] = acc[m][n][j] * scale;
      }
}

extern "C" void kernel_launch(void* const* d_in, const int* in_sizes, int n_in,
                              void* d_out, int out_size, void* d_ws, size_t ws_size,
                              hipStream_t stream) {
  (void)in_sizes; (void)n_in; (void)out_size; (void)ws_size;
  const float* x = (const float*)d_in[0];
  const float* w = (const float*)d_in[1];
  const float* scale = (const float*)d_in[2];
  float* out = (float*)d_out;

  char* ws = (char*)d_ws;
  double* part = (double*)ws;
  double* sum = (double*)(ws + 16384);
  unsigned short* Wq = (unsigned short*)(ws + 32768);
  unsigned short* Xb = (unsigned short*)(ws + 32768 + (size_t)N_DIM * K_DIM * 2);

  const long long nW = (long long)N_DIM * K_DIM;   // 67108864
  const long long nX = (long long)M_ROWS * K_DIM;  // 67108864

  absum_part_kernel<<<RED_BLOCKS, 256, 0, stream>>>((const float4*)w, part, nW / 4);
  reduce_sum_kernel<<<1, 256, 0, stream>>>(part, sum, RED_BLOCKS);
  quant_w_kernel<<<2048, 256, 0, stream>>>((const float4*)w, Wq, sum, nW / 8);
  cvt_x_kernel<<<2048, 256, 0, stream>>>((const float4*)x, Xb, nX / 8);

  const int nblocks = (M_ROWS / BM) * (N_DIM / BN);  // 4096
  gemm_bt_kernel<<<nblocks, 512, 0, stream>>>(Xb, Wq, out, scale);
}